// Round 3
// baseline (577.218 us; speedup 1.0000x reference)
//
#include <hip/hip_runtime.h>

// GCN regression: out = relu( dinv⊙(A_hat @ (dinv⊙(x@W1^T))) + b1 ) @ W2^T + b2
// A_hat = adjacency (src->dst) + self loops; dinv = rsqrt(indeg+1).
//
// Pipeline:
//   1. deg_kernel   : histogram in-degree over dst (int atomics)
//   2. scanA/B/C    : exclusive prefix sum -> CSR offsets; dinv
//   3. gemm_kernel  : g = dinv ⊙ (x @ W1^T)   (f32 vector-ALU tiled GEMM)
//   4. fill_kernel  : CSR fill (atomic cursor per dst)
//   5. agg_kernel   : per-node wave gather-sum of g rows + fused epilogue

#define SCB 512

__device__ __forceinline__ int swz(int k, int cc) {
    // element index (floats) into a [128][64] f32 tile stored as 16B slots,
    // slot XOR-swizzled by k to kill bank conflicts on strided access
    int g = cc >> 2;
    int slot = (k << 4) + (g ^ (k & 15));
    return (slot << 2) + (cc & 3);
}

__global__ __launch_bounds__(256) void deg_kernel(const int* __restrict__ dst,
                                                  int* __restrict__ degc, int E) {
    int e = blockIdx.x * 256 + threadIdx.x;
    if (e < E) atomicAdd(&degc[dst[e]], 1);
}

__global__ __launch_bounds__(SCB) void scanA_kernel(const int* __restrict__ degc,
                                                    int* __restrict__ offs,
                                                    int* __restrict__ csum, int N) {
    __shared__ int buf[2][SCB];
    int t = threadIdx.x;
    int i = blockIdx.x * SCB + t;
    int v = (i < N) ? degc[i] : 0;
    buf[0][t] = v;
    __syncthreads();
    int pi = 0;
    for (int d = 1; d < SCB; d <<= 1) {
        int val = buf[pi][t];
        if (t >= d) val += buf[pi][t - d];
        buf[pi ^ 1][t] = val;
        pi ^= 1;
        __syncthreads();
    }
    int incl = buf[pi][t];
    if (i < N) offs[i] = incl - v;           // local exclusive
    if (t == SCB - 1) csum[blockIdx.x] = incl;
}

__global__ __launch_bounds__(256) void scanB_kernel(const int* __restrict__ csum,
                                                    int* __restrict__ cbase, int NCH) {
    __shared__ int buf[2][256];
    int t = threadIdx.x;
    int v = (t < NCH) ? csum[t] : 0;
    buf[0][t] = v;
    __syncthreads();
    int pi = 0;
    for (int d = 1; d < 256; d <<= 1) {
        int val = buf[pi][t];
        if (t >= d) val += buf[pi][t - d];
        buf[pi ^ 1][t] = val;
        pi ^= 1;
        __syncthreads();
    }
    if (t < NCH) cbase[t] = buf[pi][t] - v;  // exclusive
}

__global__ __launch_bounds__(SCB) void scanC_kernel(int* __restrict__ offs,
                                                    const int* __restrict__ cbase,
                                                    const int* __restrict__ degc,
                                                    float* __restrict__ dinv, int N) {
    int i = blockIdx.x * SCB + threadIdx.x;
    if (i < N) {
        offs[i] += cbase[blockIdx.x];
        dinv[i] = rsqrtf((float)(degc[i] + 1));  // +1 = self loop
    }
}

// g[n][c] = dinv[n] * sum_k x[n][k] * W1[c][k]
// block: 256 thr, tile 64 nodes x 64 ch, thread: 4x4 register tile
__global__ __launch_bounds__(256) void gemm_kernel(const float* __restrict__ x,
                                                   const float* __restrict__ W1,
                                                   const float* __restrict__ dinv,
                                                   float* __restrict__ gbuf, int N) {
    __shared__ float xT[128 * 64];   // xT[k][node], swizzled
    __shared__ float wT[128 * 64];   // wT[k][c],   swizzled
    int t = threadIdx.x;
    int nbase = blockIdx.x * 64;

    // W1 is [64][128] row-major; store transposed+swizzled. Coalesced global read.
    for (int i = t; i < 64 * 128; i += 256) {
        int c = i >> 7, k = i & 127;
        wT[swz(k, c)] = W1[i];
    }
    // x tile: 64 nodes x 128, transposed into LDS
    for (int it = 0; it < 8; ++it) {
        int node = it * 8 + (t >> 5);
        int k4 = (t & 31) << 2;
        int n = nbase + node;
        float4 v = make_float4(0.f, 0.f, 0.f, 0.f);
        if (n < N) v = *(const float4*)&x[(size_t)n * 128 + k4];
        xT[swz(k4 + 0, node)] = v.x;
        xT[swz(k4 + 1, node)] = v.y;
        xT[swz(k4 + 2, node)] = v.z;
        xT[swz(k4 + 3, node)] = v.w;
    }
    __syncthreads();

    int tx = t & 15;   // channel group: c = tx*4 .. +3
    int ty = t >> 4;   // node group:    n = ty*4 .. +3
    float acc[4][4] = {};
#pragma unroll 4
    for (int k = 0; k < 128; ++k) {
        float4 xv = *(const float4*)&xT[swz(k, ty << 2)];
        float4 wv = *(const float4*)&wT[swz(k, tx << 2)];
        float xa[4] = {xv.x, xv.y, xv.z, xv.w};
        float wa[4] = {wv.x, wv.y, wv.z, wv.w};
#pragma unroll
        for (int i2 = 0; i2 < 4; ++i2)
#pragma unroll
            for (int j2 = 0; j2 < 4; ++j2)
                acc[i2][j2] = fmaf(xa[i2], wa[j2], acc[i2][j2]);
    }

#pragma unroll
    for (int i2 = 0; i2 < 4; ++i2) {
        int n = nbase + (ty << 2) + i2;
        if (n < N) {
            float dv = dinv[n];
            float4 o;
            o.x = dv * acc[i2][0];
            o.y = dv * acc[i2][1];
            o.z = dv * acc[i2][2];
            o.w = dv * acc[i2][3];
            *(float4*)&gbuf[(size_t)n * 64 + (tx << 2)] = o;
        }
    }
}

__global__ __launch_bounds__(256) void fill_kernel(const int* __restrict__ src,
                                                   const int* __restrict__ dst,
                                                   const int* __restrict__ offs,
                                                   int* __restrict__ cursor,
                                                   int* __restrict__ csr, int E) {
    int e = blockIdx.x * 256 + threadIdx.x;
    if (e < E) {
        int d = dst[e];
        int p = atomicAdd(&cursor[d], 1);
        csr[offs[d] + p] = src[e];
    }
}

// one wave per node: lane = channel; gather-sum g[src] rows, fused epilogue
__global__ __launch_bounds__(256) void agg_kernel(const float* __restrict__ gbuf,
                                                  const int* __restrict__ csr,
                                                  const int* __restrict__ offs,
                                                  const int* __restrict__ degc,
                                                  const float* __restrict__ dinv,
                                                  const float* __restrict__ W2,
                                                  const float* __restrict__ b1,
                                                  const float* __restrict__ b2,
                                                  float* __restrict__ out, int N) {
    int wid = (int)((blockIdx.x * 256 + threadIdx.x) >> 6);
    int lane = threadIdx.x & 63;
    if (wid >= N) return;
    int off = offs[wid];
    int cnt = degc[wid];
    float acc = gbuf[(size_t)wid * 64 + lane];  // self loop term
    for (int base = 0; base < cnt; base += 64) {
        int rem = cnt - base;
        if (rem > 64) rem = 64;
        int s = (lane < rem) ? csr[off + base + lane] : 0;
        for (int j = 0; j < rem; ++j) {
            int sj = __shfl(s, j);
            acc += gbuf[(size_t)sj * 64 + lane];
        }
    }
    float val = dinv[wid] * acc + b1[lane];
    val = fmaxf(val, 0.0f) * W2[lane];
#pragma unroll
    for (int o = 32; o >= 1; o >>= 1) val += __shfl_xor(val, o);
    if (lane == 0) out[wid] = val + b2[0];
}

extern "C" void kernel_launch(void* const* d_in, const int* in_sizes, int n_in,
                              void* d_out, int out_size, void* d_ws, size_t ws_size,
                              hipStream_t stream) {
    const float* x  = (const float*)d_in[0];
    const int*   ei = (const int*)d_in[1];
    const float* W1 = (const float*)d_in[2];
    const float* b1 = (const float*)d_in[3];
    const float* W2 = (const float*)d_in[4];
    const float* b2 = (const float*)d_in[5];
    float* out = (float*)d_out;

    int N = in_sizes[0] / 128;
    int E = in_sizes[1] / 2;
    const int* src = ei;
    const int* dst = ei + E;

    char* ws = (char*)d_ws;
    int*   degc   = (int*)(ws + 0x000000);   // N ints
    int*   offs   = (int*)(ws + 0x080000);   // N ints
    int*   cursor = (int*)(ws + 0x100000);   // N ints
    int*   csum   = (int*)(ws + 0x180000);   // NCH ints
    int*   cbase  = (int*)(ws + 0x184000);   // NCH ints
    float* dinv   = (float*)(ws + 0x190000); // N floats
    int*   csr    = (int*)(ws + 0x210000);   // E ints (12.8 MB)
    float* gbuf   = (float*)(ws + 0xE90000); // N*64 floats (25.6 MB)

    hipMemsetAsync(degc, 0, (size_t)N * 4, stream);
    hipMemsetAsync(cursor, 0, (size_t)N * 4, stream);

    int NCH = (N + SCB - 1) / SCB;  // 196 for N=100000 (scanB assumes <=256)

    deg_kernel<<<(E + 255) / 256, 256, 0, stream>>>(dst, degc, E);
    scanA_kernel<<<NCH, SCB, 0, stream>>>(degc, offs, csum, N);
    scanB_kernel<<<1, 256, 0, stream>>>(csum, cbase, NCH);
    scanC_kernel<<<NCH, SCB, 0, stream>>>(offs, cbase, degc, dinv, N);
    gemm_kernel<<<(N + 63) / 64, 256, 0, stream>>>(x, W1, dinv, gbuf, N);
    fill_kernel<<<(E + 255) / 256, 256, 0, stream>>>(src, dst, offs, cursor, csr, E);
    agg_kernel<<<(N + 3) / 4, 256, 0, stream>>>(gbuf, csr, offs, degc, dinv, W2, b1, b2, out, N);
}